// Round 8
// baseline (1690.969 us; speedup 1.0000x reference)
//
#include <hip/hip_runtime.h>
#include <hip/hip_bf16.h>

#define NN 100000
#define EE 1600000
#define NCHUNK 391    // ceil(NN/256)
#define G 256         // mega-kernel grid (1 block/CU guaranteed -> no barrier deadlock)
#define HBLK 128      // blocks doing hist in phase A

typedef __hip_bfloat16 bf16_t;
typedef int int4v __attribute__((ext_vector_type(4)));
typedef float f4 __attribute__((ext_vector_type(4)));

// ---- workspace layout (float offsets) ----
#define PARB  600000       // params fp32 4465
#define EMB   604480       // N*32
#define PBUF  3804480      // N*32
#define QBUF  7004480      // N*32
#define ABUF  10204480     // N*32 agg; aliased as rank[EE] before gather
#define SOFF  13404480     // stats[0:128], flag @128, bars @136..151
#define DEG   (SOFF + 256)
#define ROWP  (DEG + 100000)
#define BSUM  (ROWP + 100002)
#define SRCL  (BSUM + 512)

// ---- param offsets inside PARB ----
#define O_WCONT 0
#define O_BCONT 96
#define O_TCHRG 112
#define O_TPDG  136
#define O_TPV   192
#define O_WCAT  256
#define O_BCAT  640
#define O_WENC  656
#define O_BENC  1680
#define O_GALL  1712
#define O_BEALL 1744
#define O_WMSG  1776
#define O_BMSG  3824
#define O_GCONV 3856
#define O_BECONV 3888
#define O_WOUT1 3920
#define O_BOUT1 4432
#define O_WOUT2 4448
#define O_BOUT2 4464
#define NPAR    4465

__device__ __forceinline__ float bf(unsigned short u) {
    return __uint_as_float(((unsigned)u) << 16);
}
__device__ __forceinline__ f4 elu4(f4 v) {
    f4 r;
    r.x = v.x > 0.0f ? v.x : expm1f(v.x);
    r.y = v.y > 0.0f ? v.y : expm1f(v.y);
    r.z = v.z > 0.0f ? v.z : expm1f(v.z);
    r.w = v.w > 0.0f ? v.w : expm1f(v.w);
    return r;
}

// grid-wide barrier: release fence -> arrive -> spin (s_sleep backoff) -> acquire fence
__device__ __forceinline__ void gbar(int* bars, int id) {
    __syncthreads();
    if (threadIdx.x == 0) {
        __threadfence();
        atomicAdd(&bars[id], 1);
        while (atomicAdd(&bars[id], 0) < G) __builtin_amdgcn_s_sleep(16);
        __threadfence();
    }
    __syncthreads();
}

// ---------------- init: zero deg/stats/bars, detect dtype, convert params ----------------
struct InitArgs {
    const void* p[19];
    float*      par;
    int*        deg;
    float*      stats;
    int*        flagp;
    int*        bars;
};

__global__ __launch_bounds__(256) void k_init(InitArgs a)
{
    __shared__ int sflag;
    const int offs[20] = {O_WCONT,O_BCONT,O_TCHRG,O_TPDG,O_TPV,O_WCAT,O_BCAT,O_WENC,
                          O_BENC,O_GALL,O_BEALL,O_WMSG,O_BMSG,O_GCONV,O_BECONV,
                          O_WOUT1,O_BOUT1,O_WOUT2,O_BOUT2,NPAR};
    int b = blockIdx.x, tid = threadIdx.x;
    int g = b * 256 + tid;
    if (g < NN) a.deg[g] = 0;
    if (b == 0) {
        if (tid < 128) a.stats[tid] = 0.0f;
        if (tid < 16)  a.bars[tid] = 0;
        int bad = 0;
        if (tid < 64) {
            const unsigned short* w = (const unsigned short*)a.p[7];  // W_enc
            for (int i = tid; i < 1024; i += 64) {
                unsigned e = (w[i] >> 7) & 0xFFu;
                if (e >= 137u) bad = 1;   // |v|>=2^10 as bf16 -> data is really f32
            }
            unsigned long long m = __ballot(bad);
            if (tid == 0) { sflag = (m != 0ull) ? 1 : 0; *a.flagp = sflag; }
        }
        __syncthreads();
        int f32 = sflag;
        for (int i = tid; i < NPAR; i += 256) {
            int t = 0;
            while (offs[t + 1] <= i) t++;
            int l = i - offs[t];
            const void* s = a.p[t];
            a.par[i] = f32 ? ((const float*)s)[l] : bf(((const unsigned short*)s)[l]);
        }
    }
}

// ---------------- persistent mega-kernel ----------------
struct MegaArgs {
    const int*  eidx;
    const void* xc;
    const int*  xcat;
    const float* par;
    const int*  flagp;
    int* deg; int* rank; int* rowp; int* bsum; int* srcl;
    float* emb; float* P; float* Q; float* agg; float* stats;
    int* bars;
    void* out;
};

struct SA {  // embed
    f4 Wc[24]; f4 bc[4]; f4 Tc[6]; f4 Tp[14]; f4 Tv[16];
    f4 Wcat[96]; f4 bcat[4]; f4 We[256]; f4 be[8];
    float ls[64];
};
struct SB { int s[256]; };                       // scanA
struct SC {  // pq
    f4 WP[256]; f4 WQ[256]; f4 bP[8]; f4 bQ[8];
    float sc[32]; float sh[32];
};
struct SD { int s[512]; };                       // scanB
struct SE { float ls[64]; };                     // gather stats2
struct SF {  // out
    f4 W1[128]; f4 b1[4]; f4 W2[4];
    f4 sc1[8], sh1[8], sc2[8], sh2[8];
    float b2;
};
union USh { SA a; SB b; SC c; SD d; SE e; SF f; };

__global__ __launch_bounds__(256) void k_mega(MegaArgs A)
{
    __shared__ USh u;
    int b = blockIdx.x, tid = threadIdx.x;
    const int f32 = *A.flagp;

    // ================= phase A: hist+rank (b<HBLK)  |  embed+stats1 (b>=HBLK) ==========
    if (b < HBLK) {
        const int4v* dst4 = (const int4v*)(A.eidx + EE);
        int4v* rank4 = (int4v*)A.rank;
        for (int i = b * 256 + tid; i < EE / 4; i += HBLK * 256) {
            int4v d = __builtin_nontemporal_load(&dst4[i]);
            int4v r;
            r.x = atomicAdd(&A.deg[d.x], 1);
            r.y = atomicAdd(&A.deg[d.y], 1);
            r.z = atomicAdd(&A.deg[d.z], 1);
            r.w = atomicAdd(&A.deg[d.w], 1);
            rank4[i] = r;
        }
    } else {
        // load weights
        {
            float* s;
            s=(float*)u.a.Wc;   for(int i=tid;i<96;  i+=256) s[i]=A.par[O_WCONT+i];
            s=(float*)u.a.bc;   for(int i=tid;i<16;  i+=256) s[i]=A.par[O_BCONT+i];
            s=(float*)u.a.Tc;   for(int i=tid;i<24;  i+=256) s[i]=A.par[O_TCHRG+i];
            s=(float*)u.a.Tp;   for(int i=tid;i<56;  i+=256) s[i]=A.par[O_TPDG+i];
            s=(float*)u.a.Tv;   for(int i=tid;i<64;  i+=256) s[i]=A.par[O_TPV+i];
            s=(float*)u.a.Wcat; for(int i=tid;i<384; i+=256) s[i]=A.par[O_WCAT+i];
            s=(float*)u.a.bcat; for(int i=tid;i<16;  i+=256) s[i]=A.par[O_BCAT+i];
            s=(float*)u.a.We;   for(int i=tid;i<1024;i+=256) s[i]=A.par[O_WENC+i];
            s=(float*)u.a.be;   for(int i=tid;i<32;  i+=256) s[i]=A.par[O_BENC+i];
            if (tid < 64) u.a.ls[tid] = 0.0f;
        }
        __syncthreads();
        for (int c = b - HBLK; c < NCHUNK; c += G - HBLK) {
            int n = c * 256 + tid;
            if (n < NN) {
                float x0,x1,x2,x3,x4,x5;
                if (f32) {
                    const float* xr = (const float*)A.xc + (size_t)n * 6;
                    x0=xr[0]; x1=xr[1]; x2=xr[2]; x3=xr[3]; x4=xr[4]; x5=xr[5];
                } else {
                    const unsigned* xr = (const unsigned*)A.xc + (size_t)n * 3;
                    unsigned w0=xr[0], w1=xr[1], w2=xr[2];
                    x0=__uint_as_float(w0<<16); x1=__uint_as_float(w0 & 0xFFFF0000u);
                    x2=__uint_as_float(w1<<16); x3=__uint_as_float(w1 & 0xFFFF0000u);
                    x4=__uint_as_float(w2<<16); x5=__uint_as_float(w2 & 0xFFFF0000u);
                }
                f4 ec[4];
                #pragma unroll
                for (int g = 0; g < 4; g++) {
                    f4 a = u.a.bc[g];
                    a += x0*u.a.Wc[0*4+g]; a += x1*u.a.Wc[1*4+g]; a += x2*u.a.Wc[2*4+g];
                    a += x3*u.a.Wc[3*4+g]; a += x4*u.a.Wc[4*4+g]; a += x5*u.a.Wc[5*4+g];
                    ec[g] = elu4(a);
                }
                int c0 = A.xcat[n*3+0], c1 = A.xcat[n*3+1], c2 = A.xcat[n*3+2];
                int a0 = c0 < 0 ? -c0 : c0;
                int pi = (a0==1)?0:(a0==2)?1:(a0==11)?2:(a0==13)?3:(a0==22)?4:(a0==130)?5:6;
                int ci = c1 + 1;
                f4 t0a=u.a.Tc[ci*2], t0b=u.a.Tc[ci*2+1];
                f4 t1a=u.a.Tp[pi*2], t1b=u.a.Tp[pi*2+1];
                f4 t2a=u.a.Tv[c2*2], t2b=u.a.Tv[c2*2+1];
                f4 ecat[4];
                #pragma unroll
                for (int g = 0; g < 4; g++) {
                    f4 a = u.a.bcat[g];
                    #pragma unroll
                    for (int k = 0; k < 4; k++) a += t0a[k]*u.a.Wcat[(k   )*4+g];
                    #pragma unroll
                    for (int k = 0; k < 4; k++) a += t0b[k]*u.a.Wcat[(4 +k)*4+g];
                    #pragma unroll
                    for (int k = 0; k < 4; k++) a += t1a[k]*u.a.Wcat[(8 +k)*4+g];
                    #pragma unroll
                    for (int k = 0; k < 4; k++) a += t1b[k]*u.a.Wcat[(12+k)*4+g];
                    #pragma unroll
                    for (int k = 0; k < 4; k++) a += t2a[k]*u.a.Wcat[(16+k)*4+g];
                    #pragma unroll
                    for (int k = 0; k < 4; k++) a += t2b[k]*u.a.Wcat[(20+k)*4+g];
                    ecat[g] = elu4(a);
                }
                f4* o = (f4*)(A.emb + (size_t)n * 32);
                #pragma unroll
                for (int cg = 0; cg < 8; cg++) {
                    f4 a = u.a.be[cg];
                    #pragma unroll
                    for (int kg = 0; kg < 4; kg++)
                        #pragma unroll
                        for (int k = 0; k < 4; k++)
                            a += ecat[kg][k] * u.a.We[(kg*4+k)*8 + cg];
                    #pragma unroll
                    for (int kg = 0; kg < 4; kg++)
                        #pragma unroll
                        for (int k = 0; k < 4; k++)
                            a += ec[kg][k] * u.a.We[(16 + kg*4+k)*8 + cg];
                    f4 r = elu4(a);
                    o[cg] = r;
                    #pragma unroll
                    for (int k = 0; k < 4; k++) {
                        atomicAdd(&u.a.ls[cg*4+k], r[k]);
                        atomicAdd(&u.a.ls[32+cg*4+k], r[k]*r[k]);
                    }
                }
            }
        }
        __syncthreads();
        if (tid < 64) atomicAdd(&A.stats[tid], u.a.ls[tid]);
    }
    gbar(A.bars, 0);

    // ================= phase B: scanA chunks, then pq chunks =================
    for (int c = b; c < NCHUNK; c += G) {
        int i = c * 256 + tid;
        int v = (i < NN) ? A.deg[i] : 0;
        u.b.s[tid] = v;
        __syncthreads();
        for (int off = 1; off < 256; off <<= 1) {
            int x = (tid >= off) ? u.b.s[tid - off] : 0;
            __syncthreads();
            u.b.s[tid] += x;
            __syncthreads();
        }
        if (i < NN) A.rowp[i] = u.b.s[tid] - v;
        if (tid == 255) A.bsum[c] = u.b.s[255];
        __syncthreads();
    }
    // pq prep (per block)
    {
        if (tid < 32) {
            float mu  = A.stats[tid] * (1.0f / NN);
            float var = A.stats[32 + tid] * (1.0f / NN) - mu * mu;
            float s   = A.par[O_GALL + tid] * rsqrtf(var + 1e-5f);
            u.c.sc[tid] = s;
            u.c.sh[tid] = A.par[O_BEALL + tid] - mu * s;
        }
        __syncthreads();
        float* wp = (float*)u.c.WP;
        float* wq = (float*)u.c.WQ;
        for (int e = tid; e < 1024; e += 256) {
            int k = e >> 5;
            float w1 = A.par[O_WMSG + e];
            float w2 = A.par[O_WMSG + 1024 + e];
            wp[e] = u.c.sc[k] * (w1 - w2);
            wq[e] = u.c.sc[k] * w2;
        }
        if (tid < 32) {
            float aP = A.par[O_BMSG + tid], aQ = 0.0f;
            for (int k = 0; k < 32; k++) {
                float w1 = A.par[O_WMSG + k*32 + tid];
                float w2 = A.par[O_WMSG + (k+32)*32 + tid];
                aP += u.c.sh[k] * (w1 - w2);
                aQ += u.c.sh[k] * w2;
            }
            ((float*)u.c.bP)[tid] = aP;
            ((float*)u.c.bQ)[tid] = aQ;
        }
        __syncthreads();
        for (int c = b; c < NCHUNK; c += G) {
            int n = c * 256 + tid;
            if (n < NN) {
                const f4* er = (const f4*)(A.emb + (size_t)n * 32);
                f4 e[8];
                #pragma unroll
                for (int g = 0; g < 8; g++) e[g] = er[g];
                f4* pr = (f4*)(A.P + (size_t)n * 32);
                f4* qr = (f4*)(A.Q + (size_t)n * 32);
                #pragma unroll
                for (int cg = 0; cg < 8; cg++) {
                    f4 aP = u.c.bP[cg];
                    f4 aQ = u.c.bQ[cg];
                    #pragma unroll
                    for (int kg = 0; kg < 8; kg++)
                        #pragma unroll
                        for (int k = 0; k < 4; k++) {
                            float ek = e[kg][k];
                            aP += ek * u.c.WP[(kg*4+k)*8 + cg];
                            aQ += ek * u.c.WQ[(kg*4+k)*8 + cg];
                        }
                    pr[cg] = aP;
                    qr[cg] = aQ;
                }
            }
        }
    }
    gbar(A.bars, 1);

    // ================= phase C: scanB (block 0) =================
    if (b == 0) {
        int v0 = (tid < NCHUNK) ? A.bsum[tid] : 0;
        int v1 = (tid + 256 < NCHUNK) ? A.bsum[tid + 256] : 0;
        u.d.s[tid] = v0;
        u.d.s[tid + 256] = v1;
        __syncthreads();
        for (int off = 1; off < 512; off <<= 1) {
            int a0 = (tid >= off) ? u.d.s[tid - off] : 0;
            int a1 = (tid + 256 >= off) ? u.d.s[tid + 256 - off] : 0;
            __syncthreads();
            u.d.s[tid] += a0;
            u.d.s[tid + 256] += a1;
            __syncthreads();
        }
        if (tid < NCHUNK) A.bsum[tid] = u.d.s[tid] - v0;
        if (tid + 256 < NCHUNK) A.bsum[tid + 256] = u.d.s[tid + 256] - v1;
    }
    gbar(A.bars, 2);

    // ================= phase D: scanC =================
    for (int c = b; c < NCHUNK; c += G) {
        int i = c * 256 + tid;
        if (i < NN) A.rowp[i] += A.bsum[c];
    }
    if (b == 0 && tid == 0) A.rowp[NN] = EE;
    gbar(A.bars, 3);

    // ================= phase E: scatter =================
    {
        const int4v* src4 = (const int4v*)A.eidx;
        const int4v* dst4 = (const int4v*)(A.eidx + EE);
        const int4v* rnk4 = (const int4v*)A.rank;
        for (int i = b * 256 + tid; i < EE / 4; i += G * 256) {
            int4v s = __builtin_nontemporal_load(&src4[i]);
            int4v d = __builtin_nontemporal_load(&dst4[i]);
            int4v r = __builtin_nontemporal_load(&rnk4[i]);
            __builtin_nontemporal_store(s.x, &A.srcl[A.rowp[d.x] + r.x]);
            __builtin_nontemporal_store(s.y, &A.srcl[A.rowp[d.y] + r.y]);
            __builtin_nontemporal_store(s.z, &A.srcl[A.rowp[d.z] + r.z]);
            __builtin_nontemporal_store(s.w, &A.srcl[A.rowp[d.w] + r.w]);
        }
    }
    gbar(A.bars, 4);

    // ================= phase F: gather-max (wave/node) + fused stats2 =================
    {
        if (tid < 64) u.e.ls[tid] = 0.0f;
        __syncthreads();
        int lane = tid & 63;
        int wv = b * 4 + (tid >> 6);
        int slice = lane >> 3;
        int cg = lane & 7;
        const f4* Q4 = (const f4*)A.Q;
        for (int n = wv; n < NN; n += G * 4) {
            int beg = A.rowp[n], end = A.rowp[n + 1];
            f4 m = {-INFINITY, -INFINITY, -INFINITY, -INFINITY};
            for (int e = beg + slice; e < end; e += 8) {
                int s = __builtin_nontemporal_load(&A.srcl[e]);
                f4 q = Q4[(size_t)s * 8 + cg];
                m.x = fmaxf(m.x, q.x); m.y = fmaxf(m.y, q.y);
                m.z = fmaxf(m.z, q.z); m.w = fmaxf(m.w, q.w);
            }
            #pragma unroll
            for (int off = 8; off < 64; off <<= 1) {
                m.x = fmaxf(m.x, __shfl_xor(m.x, off));
                m.y = fmaxf(m.y, __shfl_xor(m.y, off));
                m.z = fmaxf(m.z, __shfl_xor(m.z, off));
                m.w = fmaxf(m.w, __shfl_xor(m.w, off));
            }
            if (lane < 8) {
                f4 o;
                if (end > beg) {
                    f4 p = ((const f4*)A.P)[(size_t)n * 8 + lane];
                    o = m + p;
                } else {
                    o = (f4){0.f, 0.f, 0.f, 0.f};
                }
                ((f4*)A.agg)[(size_t)n * 8 + lane] = o;
                #pragma unroll
                for (int k = 0; k < 4; k++) {
                    atomicAdd(&u.e.ls[lane*4+k], o[k]);
                    atomicAdd(&u.e.ls[32+lane*4+k], o[k]*o[k]);
                }
            }
        }
        __syncthreads();
        if (tid < 64) atomicAdd(&A.stats[64 + tid], u.e.ls[tid]);
    }
    gbar(A.bars, 5);

    // ================= phase G: output MLP =================
    {
        float* s = (float*)u.f.W1;
        for (int i = tid; i < 512; i += 256) s[i] = A.par[O_WOUT1 + i];
        if (tid < 16) {
            ((float*)u.f.b1)[tid] = A.par[O_BOUT1 + tid];
            ((float*)u.f.W2)[tid] = A.par[O_BOUT2 - 17 + 1 + tid];   // placeholder, fixed below
        }
        if (tid < 16) ((float*)u.f.W2)[tid] = A.par[O_WOUT2 + tid];
        if (tid < 32) {
            float mu  = A.stats[tid] * (1.0f / NN);
            float var = A.stats[32 + tid] * (1.0f / NN) - mu * mu;
            float sc  = A.par[O_GALL + tid] * rsqrtf(var + 1e-5f);
            ((float*)u.f.sc1)[tid] = sc;
            ((float*)u.f.sh1)[tid] = A.par[O_BEALL + tid] - mu * sc;
            float mu2  = A.stats[64 + tid] * (1.0f / NN);
            float var2 = A.stats[96 + tid] * (1.0f / NN) - mu2 * mu2;
            float sc2  = A.par[O_GCONV + tid] * rsqrtf(var2 + 1e-5f);
            ((float*)u.f.sc2)[tid] = sc2;
            ((float*)u.f.sh2)[tid] = A.par[O_BECONV + tid] - mu2 * sc2;
        }
        if (tid == 0) u.f.b2 = A.par[O_BOUT2];
        __syncthreads();
        for (int c = b; c < NCHUNK; c += G) {
            int n = c * 256 + tid;
            if (n < NN) {
                const f4* er = (const f4*)(A.emb + (size_t)n * 32);
                const f4* ar = (const f4*)(A.agg + (size_t)n * 32);
                f4 h[8];
                #pragma unroll
                for (int g = 0; g < 8; g++)
                    h[g] = er[g]*u.f.sc1[g] + u.f.sh1[g] + ar[g]*u.f.sc2[g] + u.f.sh2[g];
                f4 o1[4];
                #pragma unroll
                for (int g = 0; g < 4; g++) {
                    f4 acc = u.f.b1[g];
                    #pragma unroll
                    for (int kg = 0; kg < 8; kg++)
                        #pragma unroll
                        for (int k = 0; k < 4; k++)
                            acc += h[kg][k] * u.f.W1[(kg*4+k)*4 + g];
                    o1[g] = elu4(acc);
                }
                float acc = u.f.b2;
                #pragma unroll
                for (int g = 0; g < 4; g++) {
                    f4 p = o1[g] * u.f.W2[g];
                    acc += p.x + p.y + p.z + p.w;
                }
                if (f32) ((float*)A.out)[n] = acc;
                else     ((bf16_t*)A.out)[n] = __float2bfloat16(acc);
            }
        }
    }
}

extern "C" void kernel_launch(void* const* d_in, const int* in_sizes, int n_in,
                              void* d_out, int out_size, void* d_ws, size_t ws_size,
                              hipStream_t stream)
{
    float* ws    = (float*)d_ws;
    float* par   = ws + PARB;
    float* stats = ws + SOFF;
    int*   flagp = (int*)(stats + 128);
    int*   bars  = (int*)(stats + 136);

    InitArgs ia;
    for (int t = 0; t < 19; t++) ia.p[t] = d_in[4 + t];
    ia.par = par; ia.deg = (int*)(ws + DEG); ia.stats = stats;
    ia.flagp = flagp; ia.bars = bars;
    k_init<<<NCHUNK, 256, 0, stream>>>(ia);

    MegaArgs ma;
    ma.eidx = (const int*)d_in[2];
    ma.xc   = d_in[0];
    ma.xcat = (const int*)d_in[1];
    ma.par  = par;
    ma.flagp = flagp;
    ma.deg  = (int*)(ws + DEG);
    ma.rank = (int*)(ws + ABUF);
    ma.rowp = (int*)(ws + ROWP);
    ma.bsum = (int*)(ws + BSUM);
    ma.srcl = (int*)(ws + SRCL);
    ma.emb  = ws + EMB;
    ma.P    = ws + PBUF;
    ma.Q    = ws + QBUF;
    ma.agg  = ws + ABUF;
    ma.stats = stats;
    ma.bars = bars;
    ma.out  = d_out;
    k_mega<<<G, 256, 0, stream>>>(ma);
}

// Round 9
// 409.244 us; speedup vs baseline: 4.1319x; 4.1319x over previous
//
#include <hip/hip_runtime.h>
#include <hip/hip_bf16.h>

#define NN 100000
#define EE 1600000
#define NB_SCAN 391   // ceil(NN/256)
#define HB 782        // hist blocks in fusedA (8 edges/thread)
#define GB 1024       // gather blocks (grid-stride, 4 waves each)

typedef __hip_bfloat16 bf16_t;
typedef int int4v __attribute__((ext_vector_type(4)));
typedef float f4 __attribute__((ext_vector_type(4)));
typedef unsigned int u2v __attribute__((ext_vector_type(2)));

// ---- workspace layout (float offsets) ----
#define PARB  600000       // params fp32 4465
#define EMB   604480       // N*32 raw (pre-bn1) embeddings
#define PBUF  3804480      // N*32  P' (bn1+Wmsg folded)
#define QBUF  7004480      // N*32 region; Q stored as packed bf16 (N*32 ushorts)
#define ABUF  10204480     // N*32 agg; aliased as rank[EE] before gather
#define SOFF  13404480     // stats: [0:32) sum1 [32:64) sq1 [64:96) sum2 [96:128) sq2, [128] flag
#define DEG   (SOFF + 256)
#define ROWP  (DEG + 100000)
#define BSUM  (ROWP + 100002)
#define SRCL  (BSUM + 512)

// ---- param offsets inside PARB ----
#define O_WCONT 0
#define O_BCONT 96
#define O_TCHRG 112
#define O_TPDG  136
#define O_TPV   192
#define O_WCAT  256
#define O_BCAT  640
#define O_WENC  656
#define O_BENC  1680
#define O_GALL  1712
#define O_BEALL 1744
#define O_WMSG  1776
#define O_BMSG  3824
#define O_GCONV 3856
#define O_BECONV 3888
#define O_WOUT1 3920
#define O_BOUT1 4432
#define O_WOUT2 4448
#define O_BOUT2 4464
#define NPAR    4465

__device__ __forceinline__ float bf(unsigned u) {
    return __uint_as_float(u << 16);
}
__device__ __forceinline__ unsigned short f2bf(float x) {
    __hip_bfloat16 h = __float2bfloat16(x);   // RNE
    return *reinterpret_cast<unsigned short*>(&h);
}
__device__ __forceinline__ f4 elu4(f4 v) {
    f4 r;
    r.x = v.x > 0.0f ? v.x : expm1f(v.x);
    r.y = v.y > 0.0f ? v.y : expm1f(v.y);
    r.z = v.z > 0.0f ? v.z : expm1f(v.z);
    r.w = v.w > 0.0f ? v.w : expm1f(v.w);
    return r;
}

// ---------------- init: zero deg & stats; block 0 detects dtype + converts params ----------------
struct InitArgs {
    const void* p[19];
    float*      par;
    int*        deg;
    float*      stats;
    int*        flagp;
};

__global__ __launch_bounds__(256) void k_init(InitArgs a)
{
    __shared__ int sflag;
    const int offs[20] = {O_WCONT,O_BCONT,O_TCHRG,O_TPDG,O_TPV,O_WCAT,O_BCAT,O_WENC,
                          O_BENC,O_GALL,O_BEALL,O_WMSG,O_BMSG,O_GCONV,O_BECONV,
                          O_WOUT1,O_BOUT1,O_WOUT2,O_BOUT2,NPAR};
    int b = blockIdx.x, tid = threadIdx.x;
    int g = b * 256 + tid;
    if (g < NN) a.deg[g] = 0;
    if (b == 0) {
        if (tid < 128) a.stats[tid] = 0.0f;
        int bad = 0;
        if (tid < 64) {
            const unsigned short* w = (const unsigned short*)a.p[7];  // W_enc
            for (int i = tid; i < 1024; i += 64) {
                unsigned e = (w[i] >> 7) & 0xFFu;
                if (e >= 137u) bad = 1;   // |v|>=2^10 as bf16 -> tensors are really f32
            }
        }
        unsigned long long m = __ballot(bad);
        if (tid == 0) { sflag = (m != 0ull) ? 1 : 0; *a.flagp = sflag; }
        __syncthreads();
        int f32 = sflag;
        for (int i = tid; i < NPAR; i += 256) {
            int t = 0;
            while (offs[t + 1] <= i) t++;
            int l = i - offs[t];
            const void* s = a.p[t];
            a.par[i] = f32 ? ((const float*)s)[l] : bf(((const unsigned short*)s)[l]);
        }
    }
}

// ---------------- fused A: hist (blocks < HB) | embed (blocks >= HB) ----------------
__global__ __launch_bounds__(256, 1) void k_fusedA(
    const int* __restrict__ eidx, int* __restrict__ deg, int* __restrict__ rank,
    const void* __restrict__ xc, const int* __restrict__ x_cat,
    const float* __restrict__ par, const int* __restrict__ flag,
    float* __restrict__ emb)
{
    __shared__ f4 sWc4[24];
    __shared__ f4 sbc4[4];
    __shared__ f4 sTc4[6], sTp4[14], sTv4[16];
    __shared__ f4 sWcat4[96];
    __shared__ f4 sbcat4[4];
    __shared__ f4 sWe4[256];
    __shared__ f4 sbe4[8];
    int tid = threadIdx.x;
    int b = blockIdx.x;

    if (b < HB) {
        int e8 = b * 256 + tid;
        const int4v* dst4 = (const int4v*)(eidx + EE);
        int4v* rank4 = (int4v*)rank;
        #pragma unroll
        for (int h = 0; h < 2; h++) {
            int i = e8 * 2 + h;
            if (i * 4 < EE) {
                int4v d = __builtin_nontemporal_load(&dst4[i]);
                int4v r;
                r.x = atomicAdd(&deg[d.x], 1);
                r.y = atomicAdd(&deg[d.y], 1);
                r.z = atomicAdd(&deg[d.z], 1);
                r.w = atomicAdd(&deg[d.w], 1);
                rank4[i] = r;
            }
        }
        return;
    }

    {
        float* s;
        s=(float*)sWc4;   for(int i=tid;i<96;  i+=256) s[i]=par[O_WCONT+i];
        s=(float*)sbc4;   for(int i=tid;i<16;  i+=256) s[i]=par[O_BCONT+i];
        s=(float*)sTc4;   for(int i=tid;i<24;  i+=256) s[i]=par[O_TCHRG+i];
        s=(float*)sTp4;   for(int i=tid;i<56;  i+=256) s[i]=par[O_TPDG+i];
        s=(float*)sTv4;   for(int i=tid;i<64;  i+=256) s[i]=par[O_TPV+i];
        s=(float*)sWcat4; for(int i=tid;i<384; i+=256) s[i]=par[O_WCAT+i];
        s=(float*)sbcat4; for(int i=tid;i<16;  i+=256) s[i]=par[O_BCAT+i];
        s=(float*)sWe4;   for(int i=tid;i<1024;i+=256) s[i]=par[O_WENC+i];
        s=(float*)sbe4;   for(int i=tid;i<32;  i+=256) s[i]=par[O_BENC+i];
    }
    __syncthreads();

    int n = (b - HB) * 256 + tid;
    if (n >= NN) return;

    float x0,x1,x2,x3,x4,x5;
    if (*flag) {
        const float* xr = (const float*)xc + (size_t)n * 6;
        x0=xr[0]; x1=xr[1]; x2=xr[2]; x3=xr[3]; x4=xr[4]; x5=xr[5];
    } else {
        const unsigned* xr = (const unsigned*)xc + (size_t)n * 3;
        unsigned w0=xr[0], w1=xr[1], w2=xr[2];
        x0=__uint_as_float(w0<<16); x1=__uint_as_float(w0 & 0xFFFF0000u);
        x2=__uint_as_float(w1<<16); x3=__uint_as_float(w1 & 0xFFFF0000u);
        x4=__uint_as_float(w2<<16); x5=__uint_as_float(w2 & 0xFFFF0000u);
    }

    f4 ec[4];
    #pragma unroll
    for (int g = 0; g < 4; g++) {
        f4 a = sbc4[g];
        a += x0 * sWc4[0*4+g]; a += x1 * sWc4[1*4+g]; a += x2 * sWc4[2*4+g];
        a += x3 * sWc4[3*4+g]; a += x4 * sWc4[4*4+g]; a += x5 * sWc4[5*4+g];
        ec[g] = elu4(a);
    }

    int c0 = x_cat[n*3+0], c1 = x_cat[n*3+1], c2 = x_cat[n*3+2];
    int a0 = c0 < 0 ? -c0 : c0;
    int pi = (a0==1)?0:(a0==2)?1:(a0==11)?2:(a0==13)?3:(a0==22)?4:(a0==130)?5:6;
    int ci = c1 + 1;

    f4 t0a = sTc4[ci*2],  t0b = sTc4[ci*2+1];
    f4 t1a = sTp4[pi*2],  t1b = sTp4[pi*2+1];
    f4 t2a = sTv4[c2*2],  t2b = sTv4[c2*2+1];

    f4 ecat[4];
    #pragma unroll
    for (int g = 0; g < 4; g++) {
        f4 a = sbcat4[g];
        #pragma unroll
        for (int k = 0; k < 4; k++) a += t0a[k] * sWcat4[(k     )*4+g];
        #pragma unroll
        for (int k = 0; k < 4; k++) a += t0b[k] * sWcat4[(4 + k )*4+g];
        #pragma unroll
        for (int k = 0; k < 4; k++) a += t1a[k] * sWcat4[(8 + k )*4+g];
        #pragma unroll
        for (int k = 0; k < 4; k++) a += t1b[k] * sWcat4[(12 + k)*4+g];
        #pragma unroll
        for (int k = 0; k < 4; k++) a += t2a[k] * sWcat4[(16 + k)*4+g];
        #pragma unroll
        for (int k = 0; k < 4; k++) a += t2b[k] * sWcat4[(20 + k)*4+g];
        ecat[g] = elu4(a);
    }

    f4* o = (f4*)(emb + (size_t)n * 32);
    #pragma unroll
    for (int cg = 0; cg < 8; cg++) {
        f4 a = sbe4[cg];
        #pragma unroll
        for (int kg = 0; kg < 4; kg++)
            #pragma unroll
            for (int k = 0; k < 4; k++)
                a += ecat[kg][k] * sWe4[(kg*4+k)*8 + cg];
        #pragma unroll
        for (int kg = 0; kg < 4; kg++)
            #pragma unroll
            for (int k = 0; k < 4; k++)
                a += ec[kg][k] * sWe4[(16 + kg*4+k)*8 + cg];
        o[cg] = elu4(a);
    }
}

// ---------------- fused B: scanA (blocks < NB_SCAN) | stats1 (512 blocks) ----------------
__global__ __launch_bounds__(256) void k_fusedB(
    const int* __restrict__ deg, int* __restrict__ rowp, int* __restrict__ bsum,
    const float* __restrict__ emb, float* __restrict__ stats)
{
    __shared__ int s[256];
    __shared__ float ls[64];
    int tid = threadIdx.x;
    int b = blockIdx.x;
    if (b < NB_SCAN) {
        int i = b * 256 + tid;
        int v = (i < NN) ? deg[i] : 0;
        s[tid] = v;
        __syncthreads();
        for (int off = 1; off < 256; off <<= 1) {
            int x = (tid >= off) ? s[tid - off] : 0;
            __syncthreads();
            s[tid] += x;
            __syncthreads();
        }
        if (i < NN) rowp[i] = s[tid] - v;
        if (tid == 255) bsum[b] = s[255];
        return;
    }
    if (tid < 64) ls[tid] = 0.0f;
    __syncthreads();
    int sb = b - NB_SCAN;
    int idx = sb * 256 + tid;
    int stride = 512 * 256;
    int c = idx & 31;
    float sum = 0.0f, q = 0.0f;
    for (int i = idx; i < NN * 32; i += stride) {
        float v = emb[i];
        sum += v; q += v * v;
    }
    sum += __shfl_xor(sum, 32);
    q   += __shfl_xor(q, 32);
    if ((tid & 63) < 32) {
        atomicAdd(&ls[c], sum);
        atomicAdd(&ls[32 + c], q);
    }
    __syncthreads();
    if (tid < 64) atomicAdd(&stats[tid], ls[tid]);
}

__global__ __launch_bounds__(512) void k_scanB(int* __restrict__ bsum)
{
    __shared__ int s[512];
    int tid = threadIdx.x;
    int v = (tid < NB_SCAN) ? bsum[tid] : 0;
    s[tid] = v;
    __syncthreads();
    for (int off = 1; off < 512; off <<= 1) {
        int x = (tid >= off) ? s[tid - off] : 0;
        __syncthreads();
        s[tid] += x;
        __syncthreads();
    }
    if (tid < NB_SCAN) bsum[tid] = s[tid] - v;   // exclusive
}

// ---------------- fused C: scanC (blocks < NB_SCAN) | pq (NB_SCAN blocks, Q packed bf16) ----------------
__global__ __launch_bounds__(256, 1) void k_fusedC(
    int* __restrict__ rowp, const int* __restrict__ bsum,
    const float* __restrict__ par, const float* __restrict__ stats,
    const float* __restrict__ emb, float* __restrict__ P,
    unsigned int* __restrict__ Qb)
{
    __shared__ f4 sWP4[256], sWQ4[256];
    __shared__ f4 sbP4[8], sbQ4[8];
    __shared__ float ssc[32], ssh[32];
    int tid = threadIdx.x;
    int b = blockIdx.x;
    if (b < NB_SCAN) {
        int i = b * 256 + tid;
        if (i < NN) rowp[i] += bsum[b];
        if (i == 0) rowp[NN] = EE;
        return;
    }
    if (tid < 32) {
        float mu  = stats[tid] * (1.0f / NN);
        float var = stats[32 + tid] * (1.0f / NN) - mu * mu;
        float s   = par[O_GALL + tid] * rsqrtf(var + 1e-5f);
        ssc[tid] = s;
        ssh[tid] = par[O_BEALL + tid] - mu * s;
    }
    __syncthreads();
    {
        float* wp = (float*)sWP4;
        float* wq = (float*)sWQ4;
        for (int e = tid; e < 1024; e += 256) {
            int k = e >> 5;
            float w1 = par[O_WMSG + e];
            float w2 = par[O_WMSG + 1024 + e];
            wp[e] = ssc[k] * (w1 - w2);
            wq[e] = ssc[k] * w2;
        }
    }
    if (tid < 32) {
        float aP = par[O_BMSG + tid], aQ = 0.0f;
        for (int k = 0; k < 32; k++) {
            float w1 = par[O_WMSG + k*32 + tid];
            float w2 = par[O_WMSG + (k+32)*32 + tid];
            aP += ssh[k] * (w1 - w2);
            aQ += ssh[k] * w2;
        }
        ((float*)sbP4)[tid] = aP;
        ((float*)sbQ4)[tid] = aQ;
    }
    __syncthreads();

    int n = (b - NB_SCAN) * 256 + tid;
    if (n >= NN) return;

    const f4* er = (const f4*)(emb + (size_t)n * 32);
    f4 e[8];
    #pragma unroll
    for (int g = 0; g < 8; g++) e[g] = er[g];

    f4* pr = (f4*)(P + (size_t)n * 32);
    #pragma unroll
    for (int cg = 0; cg < 8; cg++) {
        f4 aP = sbP4[cg];
        f4 aQ = sbQ4[cg];
        #pragma unroll
        for (int kg = 0; kg < 8; kg++)
            #pragma unroll
            for (int k = 0; k < 4; k++) {
                float ek = e[kg][k];
                aP += ek * sWP4[(kg*4+k)*8 + cg];
                aQ += ek * sWQ4[(kg*4+k)*8 + cg];
            }
        pr[cg] = aP;
        unsigned lo = (unsigned)f2bf(aQ.x) | ((unsigned)f2bf(aQ.y) << 16);
        unsigned hi = (unsigned)f2bf(aQ.z) | ((unsigned)f2bf(aQ.w) << 16);
        Qb[(size_t)n * 16 + cg * 2]     = lo;
        Qb[(size_t)n * 16 + cg * 2 + 1] = hi;
    }
}

// ---------------- CSR: non-atomic scatter via precomputed rank, nt stores ----------------
__global__ __launch_bounds__(256) void k_scatter(const int* __restrict__ eidx,
                                                 const int* __restrict__ rank,
                                                 const int* __restrict__ rowp,
                                                 int* __restrict__ srcl)
{
    int e8 = blockIdx.x * 256 + threadIdx.x;
    const int4v* src4 = (const int4v*)eidx;
    const int4v* dst4 = (const int4v*)(eidx + EE);
    const int4v* rnk4 = (const int4v*)rank;
    #pragma unroll
    for (int h = 0; h < 2; h++) {
        int i = e8 * 2 + h;
        if (i * 4 < EE) {
            int4v s = __builtin_nontemporal_load(&src4[i]);
            int4v d = __builtin_nontemporal_load(&dst4[i]);
            int4v r = __builtin_nontemporal_load(&rnk4[i]);
            __builtin_nontemporal_store(s.x, &srcl[rowp[d.x] + r.x]);
            __builtin_nontemporal_store(s.y, &srcl[rowp[d.y] + r.y]);
            __builtin_nontemporal_store(s.z, &srcl[rowp[d.z] + r.z]);
            __builtin_nontemporal_store(s.w, &srcl[rowp[d.w] + r.w]);
        }
    }
}

// ---------------- gather-max (wave/node, bf16 Q) + fused stats2 ----------------
__global__ __launch_bounds__(256) void k_gather(
    const int* __restrict__ rowp, const int* __restrict__ srcl,
    const unsigned int* __restrict__ Qb, const float* __restrict__ P,
    float* __restrict__ agg, float* __restrict__ stats2)
{
    __shared__ float ls[64];
    int tid = threadIdx.x;
    if (tid < 64) ls[tid] = 0.0f;
    __syncthreads();
    int lane = tid & 63;
    int wv0 = blockIdx.x * 4 + (tid >> 6);
    int slice = lane >> 3;               // 0..7 edge slice
    int cg    = lane & 7;                // channel group (4 ch)
    for (int n = wv0; n < NN; n += GB * 4) {
        int beg = rowp[n], end = rowp[n + 1];
        f4 m = {-INFINITY, -INFINITY, -INFINITY, -INFINITY};
        for (int e = beg + slice; e < end; e += 8) {
            int s = __builtin_nontemporal_load(&srcl[e]);
            u2v q = *(const u2v*)(Qb + (size_t)s * 16 + cg * 2);
            f4 qq;
            qq.x = bf(q.x & 0xFFFFu); qq.y = bf(q.x >> 16);
            qq.z = bf(q.y & 0xFFFFu); qq.w = bf(q.y >> 16);
            m.x = fmaxf(m.x, qq.x); m.y = fmaxf(m.y, qq.y);
            m.z = fmaxf(m.z, qq.z); m.w = fmaxf(m.w, qq.w);
        }
        #pragma unroll
        for (int off = 8; off < 64; off <<= 1) {
            m.x = fmaxf(m.x, __shfl_xor(m.x, off));
            m.y = fmaxf(m.y, __shfl_xor(m.y, off));
            m.z = fmaxf(m.z, __shfl_xor(m.z, off));
            m.w = fmaxf(m.w, __shfl_xor(m.w, off));
        }
        if (lane < 8) {
            f4 o;
            if (end > beg) {
                f4 p = ((const f4*)P)[(size_t)n * 8 + lane];
                o = m + p;
            } else {
                o = (f4){0.f, 0.f, 0.f, 0.f};
            }
            ((f4*)agg)[(size_t)n * 8 + lane] = o;
            #pragma unroll
            for (int k = 0; k < 4; k++) {
                atomicAdd(&ls[lane*4+k], o[k]);
                atomicAdd(&ls[32+lane*4+k], o[k]*o[k]);
            }
        }
    }
    __syncthreads();
    if (tid < 64) atomicAdd(&stats2[tid], ls[tid]);
}

// ---------------- output MLP (bn1 & bn2 scales built in-block) ----------------
__global__ __launch_bounds__(256, 1) void k_out(
    const float* __restrict__ emb, const float* __restrict__ agg,
    const float* __restrict__ par, const float* __restrict__ stats,
    const int* __restrict__ flag, void* __restrict__ out)
{
    __shared__ f4 sW14[128];
    __shared__ f4 sb14[4], sW24[4];
    __shared__ f4 sc14[8], sh14[8], sc24[8], sh24[8];
    __shared__ float sb2s;
    int tid = threadIdx.x;
    {
        float* s = (float*)sW14;
        for (int i = tid; i < 512; i += 256) s[i] = par[O_WOUT1 + i];
    }
    if (tid < 16) {
        ((float*)sb14)[tid] = par[O_BOUT1 + tid];
        ((float*)sW24)[tid] = par[O_WOUT2 + tid];
    }
    if (tid < 32) {
        float mu  = stats[tid] * (1.0f / NN);
        float var = stats[32 + tid] * (1.0f / NN) - mu * mu;
        float s   = par[O_GALL + tid] * rsqrtf(var + 1e-5f);
        ((float*)sc14)[tid] = s;
        ((float*)sh14)[tid] = par[O_BEALL + tid] - mu * s;
        float mu2  = stats[64 + tid] * (1.0f / NN);
        float var2 = stats[96 + tid] * (1.0f / NN) - mu2 * mu2;
        float s2   = par[O_GCONV + tid] * rsqrtf(var2 + 1e-5f);
        ((float*)sc24)[tid] = s2;
        ((float*)sh24)[tid] = par[O_BECONV + tid] - mu2 * s2;
    }
    if (tid == 0) sb2s = par[O_BOUT2];
    __syncthreads();

    int n = blockIdx.x * 256 + tid;
    if (n >= NN) return;

    const f4* er = (const f4*)(emb + (size_t)n * 32);
    const f4* ar = (const f4*)(agg + (size_t)n * 32);
    f4 h[8];
    #pragma unroll
    for (int g = 0; g < 8; g++) {
        f4 ev = er[g];
        f4 av = ar[g];
        h[g] = ev * sc14[g] + sh14[g] + av * sc24[g] + sh24[g];
    }
    f4 o1[4];
    #pragma unroll
    for (int g = 0; g < 4; g++) {
        f4 acc = sb14[g];
        #pragma unroll
        for (int kg = 0; kg < 8; kg++)
            #pragma unroll
            for (int k = 0; k < 4; k++)
                acc += h[kg][k] * sW14[(kg*4+k)*4 + g];
        o1[g] = elu4(acc);
    }
    float acc = sb2s;
    #pragma unroll
    for (int g = 0; g < 4; g++) {
        f4 p = o1[g] * sW24[g];
        acc += p.x + p.y + p.z + p.w;
    }

    if (*flag) ((float*)out)[n] = acc;
    else       ((bf16_t*)out)[n] = __float2bfloat16(acc);
}

extern "C" void kernel_launch(void* const* d_in, const int* in_sizes, int n_in,
                              void* d_out, int out_size, void* d_ws, size_t ws_size,
                              hipStream_t stream)
{
    const void* x_cont = d_in[0];
    const int* x_cat = (const int*)d_in[1];
    const int* eidx  = (const int*)d_in[2];

    float* ws    = (float*)d_ws;
    float* par   = ws + PARB;
    float* emb   = ws + EMB;
    float* P     = ws + PBUF;
    unsigned int* Qb = (unsigned int*)(ws + QBUF);
    float* agg   = ws + ABUF;
    int*   rank  = (int*)(ws + ABUF);     // aliased: rank dead before agg written
    float* stats = ws + SOFF;
    int*   flagp = (int*)(stats + 128);
    int*   deg   = (int*)(ws + DEG);
    int*   rowp  = (int*)(ws + ROWP);
    int*   bsum  = (int*)(ws + BSUM);
    int*   srcl  = (int*)(ws + SRCL);

    InitArgs ia;
    for (int t = 0; t < 19; t++) ia.p[t] = d_in[4 + t];
    ia.par = par; ia.deg = deg; ia.stats = stats; ia.flagp = flagp;
    k_init<<<NB_SCAN, 256, 0, stream>>>(ia);

    k_fusedA<<<HB + NB_SCAN, 256, 0, stream>>>(eidx, deg, rank, x_cont, x_cat,
                                               par, flagp, emb);
    k_fusedB<<<NB_SCAN + 512, 256, 0, stream>>>(deg, rowp, bsum, emb, stats);
    k_scanB<<<1, 512, 0, stream>>>(bsum);
    k_fusedC<<<NB_SCAN * 2, 256, 0, stream>>>(rowp, bsum, par, stats, emb, P, Qb);
    k_scatter<<<HB, 256, 0, stream>>>(eidx, rank, rowp, srcl);
    k_gather<<<GB, 256, 0, stream>>>(rowp, srcl, Qb, P, agg, stats + 64);
    k_out<<<NB_SCAN, 256, 0, stream>>>(emb, agg, par, stats, flagp, d_out);
}

// Round 10
// 402.395 us; speedup vs baseline: 4.2023x; 1.0170x over previous
//
#include <hip/hip_runtime.h>
#include <hip/hip_bf16.h>

#define NN 100000
#define EE 1600000
#define NB_SCAN 391   // ceil(NN/256)
#define HB 782        // hist/scatter block count (8 edges/thread)
#define GB 2048       // gather blocks (4 waves each -> 8192 waves = full chip)

typedef __hip_bfloat16 bf16_t;
typedef int int4v __attribute__((ext_vector_type(4)));
typedef float f4 __attribute__((ext_vector_type(4)));
typedef unsigned int u4v __attribute__((ext_vector_type(4)));

// ---- workspace layout (float offsets) ----
#define PARB  600000       // params fp32 4465
#define EMB   604480       // N*32 raw (pre-bn1) embeddings
#define PBUF  3804480      // N*32  P' (bn1+Wmsg folded)
#define QBUF  7004480      // N*32 region; Q packed bf16 (N*32 ushorts)
#define ABUF  10204480     // N*32 agg; aliased as rank[EE] before gather
#define SOFF  13404480     // stats: [0:32) s1 [32:64) q1 [64:96) s2 [96:128) q2, [128] flag
#define DEG   (SOFF + 256)           // deg, then reused as FINAL row pointers
#define ROWP  (DEG + 100000)         // chunk-local exclusive scan
#define BSUM  (ROWP + 100002)
#define SRCL  (BSUM + 512)

// ---- param offsets inside PARB ----
#define O_WCONT 0
#define O_BCONT 96
#define O_TCHRG 112
#define O_TPDG  136
#define O_TPV   192
#define O_WCAT  256
#define O_BCAT  640
#define O_WENC  656
#define O_BENC  1680
#define O_GALL  1712
#define O_BEALL 1744
#define O_WMSG  1776
#define O_BMSG  3824
#define O_GCONV 3856
#define O_BECONV 3888
#define O_WOUT1 3920
#define O_BOUT1 4432
#define O_WOUT2 4448
#define O_BOUT2 4464
#define NPAR    4465

__device__ __forceinline__ float bf(unsigned u) {
    return __uint_as_float(u << 16);
}
__device__ __forceinline__ unsigned short f2bf(float x) {
    __hip_bfloat16 h = __float2bfloat16(x);   // RNE
    return *reinterpret_cast<unsigned short*>(&h);
}
__device__ __forceinline__ f4 elu4(f4 v) {
    f4 r;
    r.x = v.x > 0.0f ? v.x : expm1f(v.x);
    r.y = v.y > 0.0f ? v.y : expm1f(v.y);
    r.z = v.z > 0.0f ? v.z : expm1f(v.z);
    r.w = v.w > 0.0f ? v.w : expm1f(v.w);
    return r;
}

// ---------------- init: zero deg & stats; block 0 detects dtype + converts params ----------------
struct InitArgs {
    const void* p[19];
    float*      par;
    int*        deg;
    float*      stats;
    int*        flagp;
};

__global__ __launch_bounds__(256) void k_init(InitArgs a)
{
    __shared__ int sflag;
    const int offs[20] = {O_WCONT,O_BCONT,O_TCHRG,O_TPDG,O_TPV,O_WCAT,O_BCAT,O_WENC,
                          O_BENC,O_GALL,O_BEALL,O_WMSG,O_BMSG,O_GCONV,O_BECONV,
                          O_WOUT1,O_BOUT1,O_WOUT2,O_BOUT2,NPAR};
    int b = blockIdx.x, tid = threadIdx.x;
    int g = b * 256 + tid;
    if (g < NN) a.deg[g] = 0;
    if (b == 0) {
        if (tid < 128) a.stats[tid] = 0.0f;
        int bad = 0;
        if (tid < 64) {
            const unsigned short* w = (const unsigned short*)a.p[7];  // W_enc
            for (int i = tid; i < 1024; i += 64) {
                unsigned e = (w[i] >> 7) & 0xFFu;
                if (e >= 137u) bad = 1;   // |v|>=2^10 as bf16 -> tensors are really f32
            }
        }
        unsigned long long m = __ballot(bad);
        if (tid == 0) { sflag = (m != 0ull) ? 1 : 0; *a.flagp = sflag; }
        __syncthreads();
        int f32 = sflag;
        for (int i = tid; i < NPAR; i += 256) {
            int t = 0;
            while (offs[t + 1] <= i) t++;
            int l = i - offs[t];
            const void* s = a.p[t];
            a.par[i] = f32 ? ((const float*)s)[l] : bf(((const unsigned short*)s)[l]);
        }
    }
}

// ---------------- fused A: hist (b%3!=0) | embed (b%3==0), interleaved dispatch ----------------
__global__ __launch_bounds__(256, 1) void k_fusedA(
    const int* __restrict__ eidx, int* __restrict__ deg, int* __restrict__ rank,
    const void* __restrict__ xc, const int* __restrict__ x_cat,
    const float* __restrict__ par, const int* __restrict__ flag,
    float* __restrict__ emb)
{
    __shared__ f4 sWc4[24];
    __shared__ f4 sbc4[4];
    __shared__ f4 sTc4[6], sTp4[14], sTv4[16];
    __shared__ f4 sWcat4[96];
    __shared__ f4 sbcat4[4];
    __shared__ f4 sWe4[256];
    __shared__ f4 sbe4[8];
    int tid = threadIdx.x;
    int b = blockIdx.x;

    if (b % 3 != 0) {
        // hist block index 0..781
        int h = b - b / 3 - 1;
        int e8 = h * 256 + tid;
        const int4v* dst4 = (const int4v*)(eidx + EE);
        int4v* rank4 = (int4v*)rank;
        #pragma unroll
        for (int hh = 0; hh < 2; hh++) {
            int i = e8 * 2 + hh;
            if (i * 4 < EE) {
                int4v d = __builtin_nontemporal_load(&dst4[i]);
                int4v r;
                r.x = atomicAdd(&deg[d.x], 1);
                r.y = atomicAdd(&deg[d.y], 1);
                r.z = atomicAdd(&deg[d.z], 1);
                r.w = atomicAdd(&deg[d.w], 1);
                rank4[i] = r;
            }
        }
        return;
    }

    {
        float* s;
        s=(float*)sWc4;   for(int i=tid;i<96;  i+=256) s[i]=par[O_WCONT+i];
        s=(float*)sbc4;   for(int i=tid;i<16;  i+=256) s[i]=par[O_BCONT+i];
        s=(float*)sTc4;   for(int i=tid;i<24;  i+=256) s[i]=par[O_TCHRG+i];
        s=(float*)sTp4;   for(int i=tid;i<56;  i+=256) s[i]=par[O_TPDG+i];
        s=(float*)sTv4;   for(int i=tid;i<64;  i+=256) s[i]=par[O_TPV+i];
        s=(float*)sWcat4; for(int i=tid;i<384; i+=256) s[i]=par[O_WCAT+i];
        s=(float*)sbcat4; for(int i=tid;i<16;  i+=256) s[i]=par[O_BCAT+i];
        s=(float*)sWe4;   for(int i=tid;i<1024;i+=256) s[i]=par[O_WENC+i];
        s=(float*)sbe4;   for(int i=tid;i<32;  i+=256) s[i]=par[O_BENC+i];
    }
    __syncthreads();

    int n = (b / 3) * 256 + tid;
    if (n >= NN) return;

    float x0,x1,x2,x3,x4,x5;
    if (*flag) {
        const float* xr = (const float*)xc + (size_t)n * 6;
        x0=xr[0]; x1=xr[1]; x2=xr[2]; x3=xr[3]; x4=xr[4]; x5=xr[5];
    } else {
        const unsigned* xr = (const unsigned*)xc + (size_t)n * 3;
        unsigned w0=xr[0], w1=xr[1], w2=xr[2];
        x0=__uint_as_float(w0<<16); x1=__uint_as_float(w0 & 0xFFFF0000u);
        x2=__uint_as_float(w1<<16); x3=__uint_as_float(w1 & 0xFFFF0000u);
        x4=__uint_as_float(w2<<16); x5=__uint_as_float(w2 & 0xFFFF0000u);
    }

    f4 ec[4];
    #pragma unroll
    for (int g = 0; g < 4; g++) {
        f4 a = sbc4[g];
        a += x0 * sWc4[0*4+g]; a += x1 * sWc4[1*4+g]; a += x2 * sWc4[2*4+g];
        a += x3 * sWc4[3*4+g]; a += x4 * sWc4[4*4+g]; a += x5 * sWc4[5*4+g];
        ec[g] = elu4(a);
    }

    int c0 = x_cat[n*3+0], c1 = x_cat[n*3+1], c2 = x_cat[n*3+2];
    int a0 = c0 < 0 ? -c0 : c0;
    int pi = (a0==1)?0:(a0==2)?1:(a0==11)?2:(a0==13)?3:(a0==22)?4:(a0==130)?5:6;
    int ci = c1 + 1;

    f4 t0a = sTc4[ci*2],  t0b = sTc4[ci*2+1];
    f4 t1a = sTp4[pi*2],  t1b = sTp4[pi*2+1];
    f4 t2a = sTv4[c2*2],  t2b = sTv4[c2*2+1];

    f4 ecat[4];
    #pragma unroll
    for (int g = 0; g < 4; g++) {
        f4 a = sbcat4[g];
        #pragma unroll
        for (int k = 0; k < 4; k++) a += t0a[k] * sWcat4[(k     )*4+g];
        #pragma unroll
        for (int k = 0; k < 4; k++) a += t0b[k] * sWcat4[(4 + k )*4+g];
        #pragma unroll
        for (int k = 0; k < 4; k++) a += t1a[k] * sWcat4[(8 + k )*4+g];
        #pragma unroll
        for (int k = 0; k < 4; k++) a += t1b[k] * sWcat4[(12 + k)*4+g];
        #pragma unroll
        for (int k = 0; k < 4; k++) a += t2a[k] * sWcat4[(16 + k)*4+g];
        #pragma unroll
        for (int k = 0; k < 4; k++) a += t2b[k] * sWcat4[(20 + k)*4+g];
        ecat[g] = elu4(a);
    }

    f4* o = (f4*)(emb + (size_t)n * 32);
    #pragma unroll
    for (int cg = 0; cg < 8; cg++) {
        f4 a = sbe4[cg];
        #pragma unroll
        for (int kg = 0; kg < 4; kg++)
            #pragma unroll
            for (int k = 0; k < 4; k++)
                a += ecat[kg][k] * sWe4[(kg*4+k)*8 + cg];
        #pragma unroll
        for (int kg = 0; kg < 4; kg++)
            #pragma unroll
            for (int k = 0; k < 4; k++)
                a += ec[kg][k] * sWe4[(16 + kg*4+k)*8 + cg];
        o[cg] = elu4(a);
    }
}

// ---------------- fused B: scanA (blocks < NB_SCAN) | stats1 (512 blocks) ----------------
__global__ __launch_bounds__(256) void k_fusedB(
    const int* __restrict__ deg, int* __restrict__ rowp, int* __restrict__ bsum,
    const float* __restrict__ emb, float* __restrict__ stats)
{
    __shared__ int s[256];
    __shared__ float ls[64];
    int tid = threadIdx.x;
    int b = blockIdx.x;
    if (b < NB_SCAN) {
        int i = b * 256 + tid;
        int v = (i < NN) ? deg[i] : 0;
        s[tid] = v;
        __syncthreads();
        for (int off = 1; off < 256; off <<= 1) {
            int x = (tid >= off) ? s[tid - off] : 0;
            __syncthreads();
            s[tid] += x;
            __syncthreads();
        }
        if (i < NN) rowp[i] = s[tid] - v;
        if (tid == 255) bsum[b] = s[255];
        return;
    }
    if (tid < 64) ls[tid] = 0.0f;
    __syncthreads();
    int sb = b - NB_SCAN;
    int idx = sb * 256 + tid;
    int stride = 512 * 256;
    int c = idx & 31;
    float sum = 0.0f, q = 0.0f;
    for (int i = idx; i < NN * 32; i += stride) {
        float v = emb[i];
        sum += v; q += v * v;
    }
    sum += __shfl_xor(sum, 32);
    q   += __shfl_xor(q, 32);
    if ((tid & 63) < 32) {
        atomicAdd(&ls[c], sum);
        atomicAdd(&ls[32 + c], q);
    }
    __syncthreads();
    if (tid < 64) atomicAdd(&stats[tid], ls[tid]);
}

__global__ __launch_bounds__(512) void k_scanB(int* __restrict__ bsum)
{
    __shared__ int s[512];
    int tid = threadIdx.x;
    int v = (tid < NB_SCAN) ? bsum[tid] : 0;
    s[tid] = v;
    __syncthreads();
    for (int off = 1; off < 512; off <<= 1) {
        int x = (tid >= off) ? s[tid - off] : 0;
        __syncthreads();
        s[tid] += x;
        __syncthreads();
    }
    if (tid < NB_SCAN) bsum[tid] = s[tid] - v;   // exclusive
}

// ---------------- fused C: scanC->deg (b%4==0) | pq (b%4==1) | scatter (b%4 in {2,3}) ----------------
// scatter computes final position as rowp[d] + bsum[d>>8] + rank, so it does NOT depend
// on scanC's output; gather later reads final row pointers from deg.
__global__ __launch_bounds__(256, 1) void k_fusedC(
    const int* __restrict__ rowp, const int* __restrict__ bsum,
    int* __restrict__ degout,
    const float* __restrict__ par, const float* __restrict__ stats,
    const float* __restrict__ emb, float* __restrict__ P,
    unsigned int* __restrict__ Qb,
    const int* __restrict__ eidx, const int* __restrict__ rank,
    int* __restrict__ srcl)
{
    __shared__ f4 sWP4[256], sWQ4[256];
    __shared__ f4 sbP4[8], sbQ4[8];
    __shared__ float ssc[32], ssh[32];
    int tid = threadIdx.x;
    int b = blockIdx.x;
    int m4 = b & 3;

    if (m4 == 0) {
        int c = b >> 2;
        int i = c * 256 + tid;
        if (i < NN) degout[i] = rowp[i] + bsum[c];
        return;
    }
    if (m4 >= 2) {
        int sc = (b >> 2) * 2 + (m4 - 2);     // 0..781
        int e8 = sc * 256 + tid;
        const int4v* src4 = (const int4v*)eidx;
        const int4v* dst4 = (const int4v*)(eidx + EE);
        const int4v* rnk4 = (const int4v*)rank;
        #pragma unroll
        for (int h = 0; h < 2; h++) {
            int i = e8 * 2 + h;
            if (i * 4 < EE) {
                int4v s = __builtin_nontemporal_load(&src4[i]);
                int4v d = __builtin_nontemporal_load(&dst4[i]);
                int4v r = __builtin_nontemporal_load(&rnk4[i]);
                __builtin_nontemporal_store(s.x, &srcl[rowp[d.x] + bsum[d.x >> 8] + r.x]);
                __builtin_nontemporal_store(s.y, &srcl[rowp[d.y] + bsum[d.y >> 8] + r.y]);
                __builtin_nontemporal_store(s.z, &srcl[rowp[d.z] + bsum[d.z >> 8] + r.z]);
                __builtin_nontemporal_store(s.w, &srcl[rowp[d.w] + bsum[d.w >> 8] + r.w]);
            }
        }
        return;
    }

    // ---- pq path (b%4==1) ----
    if (tid < 32) {
        float mu  = stats[tid] * (1.0f / NN);
        float var = stats[32 + tid] * (1.0f / NN) - mu * mu;
        float s   = par[O_GALL + tid] * rsqrtf(var + 1e-5f);
        ssc[tid] = s;
        ssh[tid] = par[O_BEALL + tid] - mu * s;
    }
    __syncthreads();
    {
        float* wp = (float*)sWP4;
        float* wq = (float*)sWQ4;
        for (int e = tid; e < 1024; e += 256) {
            int k = e >> 5;
            float w1 = par[O_WMSG + e];
            float w2 = par[O_WMSG + 1024 + e];
            wp[e] = ssc[k] * (w1 - w2);
            wq[e] = ssc[k] * w2;
        }
    }
    if (tid < 32) {
        float aP = par[O_BMSG + tid], aQ = 0.0f;
        for (int k = 0; k < 32; k++) {
            float w1 = par[O_WMSG + k*32 + tid];
            float w2 = par[O_WMSG + (k+32)*32 + tid];
            aP += ssh[k] * (w1 - w2);
            aQ += ssh[k] * w2;
        }
        ((float*)sbP4)[tid] = aP;
        ((float*)sbQ4)[tid] = aQ;
    }
    __syncthreads();

    int n = (b >> 2) * 256 + tid;
    if (n >= NN) return;

    const f4* er = (const f4*)(emb + (size_t)n * 32);
    f4 e[8];
    #pragma unroll
    for (int g = 0; g < 8; g++) e[g] = er[g];

    f4* pr = (f4*)(P + (size_t)n * 32);
    #pragma unroll
    for (int cg = 0; cg < 8; cg++) {
        f4 aP = sbP4[cg];
        f4 aQ = sbQ4[cg];
        #pragma unroll
        for (int kg = 0; kg < 8; kg++)
            #pragma unroll
            for (int k = 0; k < 4; k++) {
                float ek = e[kg][k];
                aP += ek * sWP4[(kg*4+k)*8 + cg];
                aQ += ek * sWQ4[(kg*4+k)*8 + cg];
            }
        pr[cg] = aP;
        unsigned lo = (unsigned)f2bf(aQ.x) | ((unsigned)f2bf(aQ.y) << 16);
        unsigned hi = (unsigned)f2bf(aQ.z) | ((unsigned)f2bf(aQ.w) << 16);
        Qb[(size_t)n * 16 + cg * 2]     = lo;
        Qb[(size_t)n * 16 + cg * 2 + 1] = hi;
    }
}

// ---------------- gather-max (wave/node, 16 slices x 4 lanes x 16B) + fused stats2 ----------------
__global__ __launch_bounds__(256) void k_gather(
    const int* __restrict__ rowp, const int* __restrict__ srcl,
    const unsigned int* __restrict__ Qb, const float* __restrict__ P,
    float* __restrict__ agg, float* __restrict__ stats2)
{
    __shared__ float ls[64];
    int tid = threadIdx.x;
    if (tid < 64) ls[tid] = 0.0f;
    __syncthreads();
    int lane = tid & 63;
    int wv0 = blockIdx.x * 4 + (tid >> 6);
    int slice = lane >> 2;               // 0..15 edge slice
    int cg    = lane & 3;                // 16B (8 channels) per lane
    for (int n = wv0; n < NN; n += GB * 4) {
        int beg = rowp[n];
        int end = (n + 1 < NN) ? rowp[n + 1] : EE;
        f4 m0 = {-INFINITY, -INFINITY, -INFINITY, -INFINITY};
        f4 m1 = m0;
        for (int e = beg + slice; e < end; e += 16) {
            int s = __builtin_nontemporal_load(&srcl[e]);
            u4v q = *(const u4v*)(Qb + (size_t)s * 16 + cg * 4);
            f4 a, b;
            a.x = bf(q.x & 0xFFFFu); a.y = bf(q.x >> 16);
            a.z = bf(q.y & 0xFFFFu); a.w = bf(q.y >> 16);
            b.x = bf(q.z & 0xFFFFu); b.y = bf(q.z >> 16);
            b.z = bf(q.w & 0xFFFFu); b.w = bf(q.w >> 16);
            m0.x = fmaxf(m0.x, a.x); m0.y = fmaxf(m0.y, a.y);
            m0.z = fmaxf(m0.z, a.z); m0.w = fmaxf(m0.w, a.w);
            m1.x = fmaxf(m1.x, b.x); m1.y = fmaxf(m1.y, b.y);
            m1.z = fmaxf(m1.z, b.z); m1.w = fmaxf(m1.w, b.w);
        }
        #pragma unroll
        for (int off = 4; off < 64; off <<= 1) {
            m0.x = fmaxf(m0.x, __shfl_xor(m0.x, off));
            m0.y = fmaxf(m0.y, __shfl_xor(m0.y, off));
            m0.z = fmaxf(m0.z, __shfl_xor(m0.z, off));
            m0.w = fmaxf(m0.w, __shfl_xor(m0.w, off));
            m1.x = fmaxf(m1.x, __shfl_xor(m1.x, off));
            m1.y = fmaxf(m1.y, __shfl_xor(m1.y, off));
            m1.z = fmaxf(m1.z, __shfl_xor(m1.z, off));
            m1.w = fmaxf(m1.w, __shfl_xor(m1.w, off));
        }
        if (lane < 4) {
            f4 o0, o1;
            if (end > beg) {
                f4 p0 = ((const f4*)P)[(size_t)n * 8 + lane * 2];
                f4 p1 = ((const f4*)P)[(size_t)n * 8 + lane * 2 + 1];
                o0 = m0 + p0;
                o1 = m1 + p1;
            } else {
                o0 = (f4){0.f, 0.f, 0.f, 0.f};
                o1 = o0;
            }
            ((f4*)agg)[(size_t)n * 8 + lane * 2]     = o0;
            ((f4*)agg)[(size_t)n * 8 + lane * 2 + 1] = o1;
            #pragma unroll
            for (int k = 0; k < 4; k++) {
                atomicAdd(&ls[lane*8 + k], o0[k]);
                atomicAdd(&ls[lane*8 + 4 + k], o1[k]);
                atomicAdd(&ls[32 + lane*8 + k], o0[k]*o0[k]);
                atomicAdd(&ls[32 + lane*8 + 4 + k], o1[k]*o1[k]);
            }
        }
    }
    __syncthreads();
    if (tid < 64) atomicAdd(&stats2[tid], ls[tid]);
}

// ---------------- output MLP (bn1 & bn2 scales built in-block) ----------------
__global__ __launch_bounds__(256, 1) void k_out(
    const float* __restrict__ emb, const float* __restrict__ agg,
    const float* __restrict__ par, const float* __restrict__ stats,
    const int* __restrict__ flag, void* __restrict__ out)
{
    __shared__ f4 sW14[128];
    __shared__ f4 sb14[4], sW24[4];
    __shared__ f4 sc14[8], sh14[8], sc24[8], sh24[8];
    __shared__ float sb2s;
    int tid = threadIdx.x;
    {
        float* s = (float*)sW14;
        for (int i = tid; i < 512; i += 256) s[i] = par[O_WOUT1 + i];
    }
    if (tid < 16) {
        ((float*)sb14)[tid] = par[O_BOUT1 + tid];
        ((float*)sW24)[tid] = par[O_WOUT2 + tid];
    }
    if (tid < 32) {
        float mu  = stats[tid] * (1.0f / NN);
        float var = stats[32 + tid] * (1.0f / NN) - mu * mu;
        float s   = par[O_GALL + tid] * rsqrtf(var + 1e-5f);
        ((float*)sc14)[tid] = s;
        ((float*)sh14)[tid] = par[O_BEALL + tid] - mu * s;
        float mu2  = stats[64 + tid] * (1.0f / NN);
        float var2 = stats[96 + tid] * (1.0f / NN) - mu2 * mu2;
        float s2   = par[O_GCONV + tid] * rsqrtf(var2 + 1e-5f);
        ((float*)sc24)[tid] = s2;
        ((float*)sh24)[tid] = par[O_BECONV + tid] - mu2 * s2;
    }
    if (tid == 0) sb2s = par[O_BOUT2];
    __syncthreads();

    int n = blockIdx.x * 256 + tid;
    if (n >= NN) return;

    const f4* er = (const f4*)(emb + (size_t)n * 32);
    const f4* ar = (const f4*)(agg + (size_t)n * 32);
    f4 h[8];
    #pragma unroll
    for (int g = 0; g < 8; g++) {
        f4 ev = er[g];
        f4 av = ar[g];
        h[g] = ev * sc14[g] + sh14[g] + av * sc24[g] + sh24[g];
    }
    f4 o1[4];
    #pragma unroll
    for (int g = 0; g < 4; g++) {
        f4 acc = sb14[g];
        #pragma unroll
        for (int kg = 0; kg < 8; kg++)
            #pragma unroll
            for (int k = 0; k < 4; k++)
                acc += h[kg][k] * sW14[(kg*4+k)*4 + g];
        o1[g] = elu4(acc);
    }
    float acc = sb2s;
    #pragma unroll
    for (int g = 0; g < 4; g++) {
        f4 p = o1[g] * sW24[g];
        acc += p.x + p.y + p.z + p.w;
    }

    if (*flag) ((float*)out)[n] = acc;
    else       ((bf16_t*)out)[n] = __float2bfloat16(acc);
}

extern "C" void kernel_launch(void* const* d_in, const int* in_sizes, int n_in,
                              void* d_out, int out_size, void* d_ws, size_t ws_size,
                              hipStream_t stream)
{
    const void* x_cont = d_in[0];
    const int* x_cat = (const int*)d_in[1];
    const int* eidx  = (const int*)d_in[2];

    float* ws    = (float*)d_ws;
    float* par   = ws + PARB;
    float* emb   = ws + EMB;
    float* P     = ws + PBUF;
    unsigned int* Qb = (unsigned int*)(ws + QBUF);
    float* agg   = ws + ABUF;
    int*   rank  = (int*)(ws + ABUF);     // aliased: rank dead before agg written
    float* stats = ws + SOFF;
    int*   flagp = (int*)(stats + 128);
    int*   deg   = (int*)(ws + DEG);      // deg, then FINAL row pointers
    int*   rowp  = (int*)(ws + ROWP);     // chunk-local scan
    int*   bsum  = (int*)(ws + BSUM);
    int*   srcl  = (int*)(ws + SRCL);

    InitArgs ia;
    for (int t = 0; t < 19; t++) ia.p[t] = d_in[4 + t];
    ia.par = par; ia.deg = deg; ia.stats = stats; ia.flagp = flagp;
    k_init<<<NB_SCAN, 256, 0, stream>>>(ia);

    k_fusedA<<<HB + NB_SCAN, 256, 0, stream>>>(eidx, deg, rank, x_cont, x_cat,
                                               par, flagp, emb);
    k_fusedB<<<NB_SCAN + 512, 256, 0, stream>>>(deg, rowp, bsum, emb, stats);
    k_scanB<<<1, 512, 0, stream>>>(bsum);
    k_fusedC<<<NB_SCAN * 4, 256, 0, stream>>>(rowp, bsum, deg, par, stats, emb, P, Qb,
                                              eidx, rank, srcl);
    k_gather<<<GB, 256, 0, stream>>>(deg, srcl, Qb, P, agg, stats + 64);
    k_out<<<NB_SCAN, 256, 0, stream>>>(emb, agg, par, stats, flagp, d_out);
}